// Round 4
// baseline (1591.865 us; speedup 1.0000x reference)
//
#include <hip/hip_runtime.h>
#include <hip/hip_bf16.h>

#define BF16 __hip_bfloat16

typedef __bf16 bf16x8 __attribute__((ext_vector_type(8)));
typedef float f32x4 __attribute__((ext_vector_type(4)));

__device__ __forceinline__ void async_copy16(const void* g, void* l) {
    __builtin_amdgcn_global_load_lds(
        (const __attribute__((address_space(1))) void*)g,
        (__attribute__((address_space(3))) void*)l,
        16, 0, 0);
}

// ---------------- fp32 -> bf16 convert with K padding ----------------
__global__ __launch_bounds__(256) void convert_pad_k(
    const float* __restrict__ src, BF16* __restrict__ dst,
    long pairs, int Ks, int Kd) {
    long p = (long)blockIdx.x * blockDim.x + threadIdx.x;
    if (p >= pairs) return;
    long e = p * 2;
    long r = e / Kd;
    int k = (int)(e - r * Kd);
    float a = (k < Ks) ? src[r * Ks + k] : 0.f;
    float b = (k + 1 < Ks) ? src[r * Ks + k + 1] : 0.f;
    dst[e] = __float2bfloat16(a);
    dst[e + 1] = __float2bfloat16(b);
}

// ---------------- fused QKV NT GEMM, BK=64 as two 32-wide sub-tiles ----------------
// X: [N][K] bf16, W packed: [1536][K] = Wq|Wk|Wv. grid (12, 260): x = m-tile, y = n-tile.
// sel = x>>2 routes output: Q rows, K rows, V (vtmode: transposed [bb][c][96], else rows).
__global__ __launch_bounds__(256, 3) void gemm_qkv(
    const BF16* __restrict__ Xg, const BF16* __restrict__ Wg,
    const float* __restrict__ bqp, const float* __restrict__ bkp, const float* __restrict__ bvp,
    BF16* __restrict__ Qo, BF16* __restrict__ Ko, BF16* __restrict__ Vo,
    int K, int vtmode) {
    __shared__ __align__(16) BF16 Xs[2][128 * 32];
    __shared__ __align__(16) BF16 Ws[2][128 * 32];
    const int tid = threadIdx.x;
    const int w = tid >> 6;
    const int lane = tid & 63;
    const int quad = lane >> 4;
    const int l15 = lane & 15;
    const long n0 = (long)blockIdx.y * 128;
    const int m0full = blockIdx.x * 128;
    const int sel = blockIdx.x >> 2;
    const int mbase = (blockIdx.x & 3) * 128;
    const int wn = (w & 1) * 64;
    const int wm = (w >> 1) * 64;
    const int srow = lane >> 2;
    const int skoff = (lane & 3) * 8;
    f32x4 acc[4][4] = {};
    for (int k0 = 0; k0 < K; k0 += 64) {
#pragma unroll
        for (int sub = 0; sub < 2; ++sub) {
#pragma unroll
            for (int c = 0; c < 2; ++c) {
                const int rbase = w * 32 + c * 16;
                const int kcol = k0 + sub * 32 + skoff;
                async_copy16(Xg + (n0 + rbase + srow) * K + kcol, &Xs[sub][rbase * 32]);
                async_copy16(Wg + (long)(m0full + rbase + srow) * K + kcol, &Ws[sub][rbase * 32]);
            }
        }
        __syncthreads();
#pragma unroll
        for (int sub = 0; sub < 2; ++sub) {
            bf16x8 af[4], bfr[4];
#pragma unroll
            for (int i = 0; i < 4; ++i)
                af[i] = *(const bf16x8*)&Xs[sub][(wn + i * 16 + l15) * 32 + quad * 8];
#pragma unroll
            for (int j = 0; j < 4; ++j)
                bfr[j] = *(const bf16x8*)&Ws[sub][(wm + j * 16 + l15) * 32 + quad * 8];
#pragma unroll
            for (int i = 0; i < 4; ++i)
#pragma unroll
                for (int j = 0; j < 4; ++j)
                    acc[i][j] = __builtin_amdgcn_mfma_f32_16x16x32_bf16(af[i], bfr[j], acc[i][j], 0, 0, 0);
        }
        __syncthreads();
    }
    const float* bp = (sel == 0) ? bqp : (sel == 1) ? bkp : bvp;
    BF16* out = (sel == 0) ? Qo : (sel == 1) ? Ko : Vo;
#pragma unroll
    for (int j = 0; j < 4; ++j) {
        const int m = mbase + wm + j * 16 + l15;
        const float bz = bp[m];
#pragma unroll
        for (int i = 0; i < 4; ++i) {
#pragma unroll
            for (int r = 0; r < 4; ++r) {
                const long n = n0 + wn + i * 16 + quad * 4 + r;
                float v = acc[i][j][r] + bz;
                if (sel == 2) {
                    v = (v >= 0.f) ? v : 0.01f * v;
                    if (vtmode) {
                        const int ni = (int)n;
                        const int bb = ni / 65;
                        const int l = ni - bb * 65;
                        out[((long)bb * 512 + m) * 96 + l] = __float2bfloat16(v);
                        continue;
                    }
                }
                out[n * 512 + m] = __float2bfloat16(v);
            }
        }
    }
}

// ---------------- V transpose (layer 0 only): Vb[n][512] -> Vt[bb][c][96] ----------------
__global__ __launch_bounds__(256) void vtrans_k(const ushort* __restrict__ Vb,
                                                ushort* __restrict__ Vt) {
    const int bb = blockIdx.x;
    for (int idx = threadIdx.x; idx < 512 * 33; idx += 256) {
        const int c = idx / 33;
        const int m = (idx - c * 33) * 2;
        ushort a = Vb[((long)bb * 65 + m) * 512 + c];
        ushort b = (m + 1 < 65) ? Vb[((long)bb * 65 + m + 1) * 512 + c] : (ushort)0;
        *(uint*)&Vt[((long)bb * 512 + c) * 96 + m] = (uint)a | ((uint)b << 16);
    }
}

// ---------------- fully fused attention, ONE WAVE per batch ----------------
// Q,K: [33280][512] bf16; Vt: [bb][c][96] bf16; X: [33280][512] in/out.
// Scores: A/B frags straight from global, 25 acc tiles in-register, no barriers.
// Softmax: shuffle-only (row r lives in quad (r&15)>>2 across 16 l15 lanes).
// P: wave-local LDS round trip (C-layout -> A-layout), unnormalized; 1/sum stays
// in registers (same quad mapping in PV epilogue). PV: V frags from global Vt.
__global__ __launch_bounds__(64) void attn_wave(
    const BF16* __restrict__ Qg, const BF16* __restrict__ Kg,
    const BF16* __restrict__ Vt, BF16* __restrict__ Xg, int residual) {
    constexpr float SC = 0.04419417382415922f;  // 1/sqrt(512)
    __shared__ __align__(16) BF16 Ps[80 * 104];
    const int bb = blockIdx.x;
    const int lane = threadIdx.x & 63;
    const int quad = lane >> 4, l15 = lane & 15;
    // zero P (pad rows/cols must be 0 for PV)
    for (int e = lane; e < 1040; e += 64) ((uint4*)Ps)[e] = make_uint4(0, 0, 0, 0);
    // clamped row addresses (rows >= 65 alias row 0; their S rows/cols are masked)
    long qrow[5], krow[5];
#pragma unroll
    for (int i = 0; i < 5; ++i) {
        int r = i * 16 + l15;
        r = (r < 65) ? r : 0;
        qrow[i] = ((long)bb * 65 + r) * 512;
        krow[i] = qrow[i];
    }
    // ---- phase 1: S = Q K^T (25 16x16 tiles in-register) ----
    f32x4 acc[25] = {};
#pragma unroll 4
    for (int k0 = 0; k0 < 512; k0 += 32) {
        bf16x8 qa[5], kb[5];
#pragma unroll
        for (int i = 0; i < 5; ++i) qa[i] = *(const bf16x8*)(Qg + qrow[i] + k0 + quad * 8);
#pragma unroll
        for (int j = 0; j < 5; ++j) kb[j] = *(const bf16x8*)(Kg + krow[j] + k0 + quad * 8);
#pragma unroll
        for (int i = 0; i < 5; ++i)
#pragma unroll
            for (int j = 0; j < 5; ++j)
                acc[i * 5 + j] = __builtin_amdgcn_mfma_f32_16x16x32_bf16(qa[i], kb[j], acc[i * 5 + j], 0, 0, 0);
    }
    __syncthreads();  // Ps zero-fill complete before phase-2 writes
    // ---- phase 2: softmax via shuffles; write unnormalized P to LDS ----
    float invv[5][4];
#pragma unroll
    for (int i = 0; i < 5; ++i) {
#pragma unroll
        for (int r = 0; r < 4; ++r) {
            float s0 = acc[i * 5 + 0][r] * SC;
            float s1 = acc[i * 5 + 1][r] * SC;
            float s2 = acc[i * 5 + 2][r] * SC;
            float s3 = acc[i * 5 + 3][r] * SC;
            float s4 = acc[i * 5 + 4][r] * SC;  // col 64+l15: only l15==0 valid
            float mx = fmaxf(fmaxf(s0, s1), fmaxf(s2, s3));
            mx = fmaxf(mx, (l15 == 0) ? s4 : -1e30f);
            mx = fmaxf(mx, __shfl_xor(mx, 1));
            mx = fmaxf(mx, __shfl_xor(mx, 2));
            mx = fmaxf(mx, __shfl_xor(mx, 4));
            mx = fmaxf(mx, __shfl_xor(mx, 8));
            float e0 = __expf(s0 - mx), e1 = __expf(s1 - mx);
            float e2 = __expf(s2 - mx), e3 = __expf(s3 - mx);
            float e4 = (l15 == 0) ? __expf(s4 - mx) : 0.f;
            float sum = e0 + e1 + e2 + e3 + e4;
            sum += __shfl_xor(sum, 1);
            sum += __shfl_xor(sum, 2);
            sum += __shfl_xor(sum, 4);
            sum += __shfl_xor(sum, 8);
            invv[i][r] = 1.f / sum;
            const int row = i * 16 + quad * 4 + r;
            if (row < 65) {
                Ps[row * 104 + 0 * 16 + l15] = __float2bfloat16(e0);
                Ps[row * 104 + 1 * 16 + l15] = __float2bfloat16(e1);
                Ps[row * 104 + 2 * 16 + l15] = __float2bfloat16(e2);
                Ps[row * 104 + 3 * 16 + l15] = __float2bfloat16(e3);
                if (l15 == 0) Ps[row * 104 + 64] = __float2bfloat16(e4);
            }
        }
    }
    __syncthreads();  // P visible for A-frag reads
    // ---- phase 3: O = (P V) * inv (+X) ----
    bf16x8 af[5][3];
#pragma unroll
    for (int i = 0; i < 5; ++i)
#pragma unroll
        for (int ks = 0; ks < 3; ++ks)
            af[i][ks] = *(const bf16x8*)&Ps[(i * 16 + l15) * 104 + ks * 32 + quad * 8];
    const long vbase = (long)bb * 512 * 96;
#pragma unroll 2
    for (int jt = 0; jt < 32; ++jt) {
        const int c = jt * 16 + l15;
        const BF16* vp = Vt + vbase + (long)c * 96 + quad * 8;
        bf16x8 b0 = *(const bf16x8*)vp;
        bf16x8 b1 = *(const bf16x8*)(vp + 32);
        bf16x8 b2 = *(const bf16x8*)(vp + 64);
        f32x4 po[5] = {};
#pragma unroll
        for (int i = 0; i < 5; ++i) {
            po[i] = __builtin_amdgcn_mfma_f32_16x16x32_bf16(af[i][0], b0, po[i], 0, 0, 0);
            po[i] = __builtin_amdgcn_mfma_f32_16x16x32_bf16(af[i][1], b1, po[i], 0, 0, 0);
            po[i] = __builtin_amdgcn_mfma_f32_16x16x32_bf16(af[i][2], b2, po[i], 0, 0, 0);
        }
#pragma unroll
        for (int i = 0; i < 5; ++i)
#pragma unroll
            for (int r = 0; r < 4; ++r) {
                const int row = i * 16 + quad * 4 + r;
                if (row < 65) {
                    const long idx = ((long)bb * 65 + row) * 512 + c;
                    float v = po[i][r] * invv[i][r];
                    if (residual) v += __bfloat162float(Xg[idx]);
                    Xg[idx] = __float2bfloat16(v);
                }
            }
    }
}

// ---------------- mean over L -> Hp[b][s*512+c] fp32 ----------------
__global__ __launch_bounds__(256) void pool_k(const BF16* __restrict__ Xg,
                                              float* __restrict__ Hp) {
    const int sb = blockIdx.x;
    const int s = sb >> 8, b = sb & 255;
    for (int c = threadIdx.x; c < 512; c += 256) {
        float acc = 0.f;
        for (int l = 0; l < 65; ++l)
            acc += __bfloat162float(Xg[((long)sb * 65 + l) * 512 + c]);
        Hp[(long)b * 1024 + s * 512 + c] = acc * (1.f / 65.f);
    }
}

// ---------------- classifier ----------------
__global__ __launch_bounds__(256) void fc_k(
    const float* __restrict__ Hp, const float* __restrict__ W1,
    const float* __restrict__ b1, const float* __restrict__ W2,
    const float* __restrict__ b2, float* __restrict__ out) {
    __shared__ float h[1024];
    __shared__ float h1[256];
    const int b = blockIdx.x, tid = threadIdx.x;
    for (int k = tid; k < 1024; k += 256) h[k] = Hp[(long)b * 1024 + k];
    __syncthreads();
    float acc = b1[tid];
    for (int k = 0; k < 1024; ++k) acc += W1[(long)tid * 1024 + k] * h[k];
    h1[tid] = fmaxf(acc, 0.f);
    __syncthreads();
    const int w = tid >> 6, lane = tid & 63;
    if (w < 2) {
        float p = 0.f;
        for (int u = lane; u < 256; u += 64) p += W2[w * 256 + u] * h1[u];
        for (int off = 32; off > 0; off >>= 1) p += __shfl_down(p, off);
        if (lane == 0) out[b * 2 + w] = p + b2[w];
    }
}

extern "C" void kernel_launch(void* const* d_in, const int* in_sizes, int n_in,
                              void* d_out, int out_size, void* d_ws, size_t ws_size,
                              hipStream_t stream) {
    const float* dataL = (const float*)d_in[0];
    const float* dataR = (const float*)d_in[1];
    const float* Wq0 = (const float*)d_in[2];
    const float* bq0 = (const float*)d_in[3];
    const float* Wk0 = (const float*)d_in[4];
    const float* bk0 = (const float*)d_in[5];
    const float* Wv0 = (const float*)d_in[6];
    const float* bv0 = (const float*)d_in[7];
    const float* Wq = (const float*)d_in[8];
    const float* bq = (const float*)d_in[9];
    const float* Wk = (const float*)d_in[10];
    const float* bk = (const float*)d_in[11];
    const float* Wv = (const float*)d_in[12];
    const float* bv = (const float*)d_in[13];
    const float* W1 = (const float*)d_in[14];
    const float* b1 = (const float*)d_in[15];
    const float* W2 = (const float*)d_in[16];
    const float* b2 = (const float*)d_in[17];

    // ws layout (bytes):
    //   Xb @ 0          : 33280 x 2112 bf16 = 140,574,720 (dead after L0 GEMM; region reused:)
    //     X  @ 0        : 34,078,720
    //     Vt @ 34078720 : 512*512*96*2 = 50,331,648  (ends 84,410,368)
    //     Hp @ 90800128 : 256*1024*4   = 1,048,576
    //   Wc @ 140574720  : w0 1536x2112 bf16 = 6,488,064 ; wl 9x512x512 bf16 = 4,718,592
    //   Qb @ 151781376  : 34,078,720
    //   Kb @ 185860096  : 34,078,720
    //   Vb @ 219938816  : 34,078,720
    char* ws = (char*)d_ws;
    BF16* Xb = (BF16*)ws;
    BF16* X = Xb;
    BF16* Vt = (BF16*)(ws + 34078720L);
    float* Hp = (float*)(ws + 90800128L);
    BF16* Wc = (BF16*)(ws + 140574720L);
    BF16* Qb = (BF16*)(ws + 151781376L);
    BF16* Kb = (BF16*)(ws + 185860096L);
    BF16* Vb = (BF16*)(ws + 219938816L);

    BF16* w0 = Wc;                      // packed [1536][2112]: Wq0|Wk0|Wv0
    BF16* wl = Wc + 3L * 512 * 2112;    // 3 layers, each packed [1536][512]

    auto cvt = [&](const float* src, BF16* dst, long R, int Ks, int Kd) {
        long pairs = R * Kd / 2;
        int blocks = (int)((pairs + 255) / 256);
        convert_pad_k<<<blocks, 256, 0, stream>>>(src, dst, pairs, Ks, Kd);
    };
    cvt(dataL, Xb, 16640, 2053, 2112);
    cvt(dataR, Xb + 16640L * 2112, 16640, 2053, 2112);
    cvt(Wq0, w0, 512, 2053, 2112);
    cvt(Wk0, w0 + 512L * 2112, 512, 2053, 2112);
    cvt(Wv0, w0 + 2L * 512 * 2112, 512, 2053, 2112);
    for (int n = 0; n < 3; ++n) {
        BF16* base = wl + (long)n * 3 * 262144;
        cvt(Wq + (long)n * 262144, base, 512, 512, 512);
        cvt(Wk + (long)n * 262144, base + 262144, 512, 512, 512);
        cvt(Wv + (long)n * 262144, base + 2 * 262144, 512, 512, 512);
    }

    dim3 ggrid(12, 260);
    // layer 0: V to row layout (Xb still live), then transpose
    gemm_qkv<<<ggrid, 256, 0, stream>>>(Xb, w0, bq0, bk0, bv0, Qb, Kb, Vb, 2112, 0);
    vtrans_k<<<512, 256, 0, stream>>>((const ushort*)Vb, (ushort*)Vt);
    attn_wave<<<512, 64, 0, stream>>>(Qb, Kb, Vt, X, 0);
    // layers 1..3: V written transposed directly by the GEMM epilogue
    for (int n = 0; n < 3; ++n) {
        gemm_qkv<<<ggrid, 256, 0, stream>>>(X, wl + (long)n * 3 * 262144,
                                            bq + n * 512, bk + n * 512, bv + n * 512,
                                            Qb, Kb, Vt, 512, 1);
        attn_wave<<<512, 64, 0, stream>>>(Qb, Kb, Vt, X, 1);
    }
    pool_k<<<512, 256, 0, stream>>>(X, Hp);
    fc_k<<<256, 256, 0, stream>>>(Hp, W1, b1, W2, b2, (float*)d_out);
}